// Round 5
// baseline (332.460 us; speedup 1.0000x reference)
//
#include <hip/hip_runtime.h>
#include <hip/hip_bf16.h>

using u16 = unsigned short;
using u32 = unsigned int;
typedef __attribute__((ext_vector_type(8))) short short8;  // 8 bf16 (4 VGPRs)
typedef __attribute__((ext_vector_type(4))) float f32x4;   // MFMA 16x16 C/D

#define MFMA16(A, B, C) __builtin_amdgcn_mfma_f32_16x16x32_bf16((A), (B), (C), 0, 0, 0)

// ---------- bf16 helpers ----------
__device__ __forceinline__ u16 f2bf(float f) {
  union { float f; u32 i; } v; v.f = f;
  u32 x = v.i;
  return (u16)((x + 0x7fffu + ((x >> 16) & 1u)) >> 16);  // RNE
}
__device__ __forceinline__ u32 pkbf(float a, float b) {
  union { __hip_bfloat162 h; u32 u; } v;
  v.h = __float22bfloat162_rn(make_float2(a, b));
  return v.u;
}
// async global->LDS, 16B/lane; LDS dest = wave-uniform base + lane*16
__device__ __forceinline__ void gl16(const u16* g, u16* l) {
  __builtin_amdgcn_global_load_lds(
      (const __attribute__((address_space(1))) u32*)g,
      (__attribute__((address_space(3))) u32*)l, 16, 0, 0);
}

// ============================================================
// Prep A: ft fp32 -> Xbf bf16 (16384x512)
// ============================================================
__global__ __launch_bounds__(256) void conv_x(const float* __restrict__ X,
                                              u16* __restrict__ Xbf) {
  const int i = (blockIdx.x * 256 + threadIdx.x) * 8;
  float4 a = *(const float4*)(X + i);
  float4 b = *(const float4*)(X + i + 4);
  uint4 o;
  o.x = pkbf(a.x, a.y); o.y = pkbf(a.z, a.w);
  o.z = pkbf(b.x, b.y); o.w = pkbf(b.z, b.w);
  *(uint4*)(Xbf + i) = o;
}

// ============================================================
// Prep B: transpose+convert W[512][N] fp32 -> Wt[N][512] bf16
// ============================================================
__global__ __launch_bounds__(256) void transpose_w(
    const float* __restrict__ Wq, const float* __restrict__ Wo,
    u16* __restrict__ Wqt, u16* __restrict__ Wot) {
  const int z = blockIdx.z;
  if (z == 1 && blockIdx.x >= 16) return;
  const float* src = z ? Wo : Wq;
  u16* dst = z ? Wot : Wqt;
  const int ncols = z ? 512 : 1536;
  __shared__ float tile[32][33];
  const int t = threadIdx.x;
  const int kt = blockIdx.y * 32, nt = blockIdx.x * 32;
  const int r = t >> 3, c4 = (t & 7) * 4;
  float4 v = *(const float4*)(src + (size_t)(kt + r) * ncols + nt + c4);
  tile[r][c4 + 0] = v.x; tile[r][c4 + 1] = v.y;
  tile[r][c4 + 2] = v.z; tile[r][c4 + 3] = v.w;
  __syncthreads();
  uint2 p = make_uint2(pkbf(tile[c4 + 0][r], tile[c4 + 1][r]),
                       pkbf(tile[c4 + 2][r], tile[c4 + 3][r]));
  *(uint2*)(dst + (size_t)(nt + r) * 512 + kt + c4) = p;
}

// ============================================================
// Kernel 1: QKV GEMM, m97-style staging with global-pointer XOR
// swizzle. Q pre-scaled by 0.125*log2(e) so attention softmax can
// use native v_exp_f32 (2^x) directly (softmax is shift-invariant).
// -> Qp[b][h][n][64]*SCALE*log2e, Kp[b][h][n][64], Vt[b][h][64][n]
// ============================================================
__global__ __launch_bounds__(256) void qkv_gemm(
    const u16* __restrict__ Xbf, const u16* __restrict__ Wt,
    const float* __restrict__ Bias,
    u16* __restrict__ Qp, u16* __restrict__ Kp, u16* __restrict__ Vt) {
  __shared__ u16 Xs[128][32];  // [m][k] unpadded, 64 B rows
  __shared__ u16 Ws[128][32];  // [n][k]
  const int t = threadIdx.x;
  const int bm = blockIdx.y * 128, bn = blockIdx.x * 128;
  const int w = t >> 6, lane = t & 63, quad = lane >> 4, l16 = lane & 15;
  const int mtb = (w >> 1) * 64, ntb = (w & 1) * 64;
  const int rr = lane >> 2;                                  // row in 16-row group
  const int gch = ((lane & 3) ^ ((lane >> 3) & 3)) * 8;      // swizzled global chunk
  const int sw = (quad ^ ((l16 >> 1) & 3)) * 8;              // frag-read chunk

  const u16* xg0 = Xbf + (size_t)(bm + w * 16 + rr) * 512 + gch;
  const u16* xg1 = xg0 + (size_t)64 * 512;
  const u16* wg0 = Wt + (size_t)(bn + w * 16 + rr) * 512 + gch;
  const u16* wg1 = wg0 + (size_t)64 * 512;
  u16* xl0 = &Xs[w * 16][0]; u16* xl1 = &Xs[64 + w * 16][0];
  u16* wl0 = &Ws[w * 16][0]; u16* wl1 = &Ws[64 + w * 16][0];

  f32x4 acc[4][4];
  const f32x4 z4 = {0.f, 0.f, 0.f, 0.f};
  #pragma unroll
  for (int mi = 0; mi < 4; mi++)
    #pragma unroll
    for (int ni = 0; ni < 4; ni++) acc[mi][ni] = z4;

  for (int k0 = 0; k0 < 512; k0 += 32) {
    gl16(xg0 + k0, xl0);
    gl16(xg1 + k0, xl1);
    gl16(wg0 + k0, wl0);
    gl16(wg1 + k0, wl1);
    __syncthreads();  // drain DMA (vmcnt0) + visibility
    short8 af[4], bf4[4];
    #pragma unroll
    for (int mi = 0; mi < 4; mi++)
      af[mi] = *(const short8*)&Xs[mtb + mi * 16 + l16][sw];
    #pragma unroll
    for (int ni = 0; ni < 4; ni++)
      bf4[ni] = *(const short8*)&Ws[ntb + ni * 16 + l16][sw];
    #pragma unroll
    for (int mi = 0; mi < 4; mi++)
      #pragma unroll
      for (int ni = 0; ni < 4; ni++)
        acc[mi][ni] = MFMA16(af[mi], bf4[ni], acc[mi][ni]);
    __syncthreads();  // reads done before next DMA overwrites
  }

  // epilogue: C-layout (row=quad*4+r, col=l16) -> packed Q/K/V
  #pragma unroll
  for (int ni = 0; ni < 4; ni++) {
    const int g = bn + ntb + ni * 16;
    const int h = g / 192, rm = g % 192;
    const int type = rm >> 6, dbase = rm & 63;
    const float bias = Bias[g + l16];
    // fold softmax scale AND log2(e) into Q so attn uses exp2 natively
    const float qsc = (type == 0) ? 0.125f * 1.44269504088896340736f : 1.0f;
    #pragma unroll
    for (int mi = 0; mi < 4; mi++) {
      const int row0 = bm + mtb + mi * 16 + quad * 4;
      const int b = row0 >> 10, n0 = row0 & 1023;
      const size_t bh = (size_t)(b * 8 + h) * 65536;
      if (type == 2) {  // V -> Vt[b][h][d][n]
        uint2 p = make_uint2(pkbf(acc[mi][ni][0] + bias, acc[mi][ni][1] + bias),
                             pkbf(acc[mi][ni][2] + bias, acc[mi][ni][3] + bias));
        *(uint2*)(Vt + bh + (size_t)(dbase + l16) * 1024 + n0) = p;
      } else {
        u16* dst = (type ? Kp : Qp) + bh;
        #pragma unroll
        for (int r = 0; r < 4; r++)
          dst[(size_t)(n0 + r) * 64 + dbase + l16] =
              f2bf((acc[mi][ni][r] + bias) * qsc);
      }
    }
  }
}

// ============================================================
// Kernel 2 v8: flash attention, S^T formulation, no P LDS, no
// online-max (v6 math), DMA staging w/ pre-swizzled global source
// (v7), NOW DOUBLE-BUFFERED (T3 minimum 2-phase pipeline):
//   prologue STAGE(buf0); loop kt: STAGE(buf^1, kt+1) -> compute
//   buf -> ONE barrier (implicit vmcnt0 drains a DMA that had the
//   whole 32-MFMA+softmax phase to land). Removes the per-kt
//   serialized DMA drain of v7 and halves barrier count.
// Race check: buf B^1 written at kt was last READ at kt-1, fenced
// by the kt-1 barrier; reads of B are fenced by the kt barrier
// before kt+1 overwrites it. Full unroll -> all offsets static.
// s_setprio(1) wraps both MFMA clusters (T5; staging/compute role
// diversity across waves now exists for the scheduler to arbitrate).
// ============================================================
__global__ __launch_bounds__(512, 4) void attn_mfma(
    const u16* __restrict__ Qp, const u16* __restrict__ Kp,
    const u16* __restrict__ Vt, u16* __restrict__ ATT) {
  __shared__ u16 Ks[2][128][64];   // [buf][key][d]   linear, swizzled content
  __shared__ u16 Vs[2][64][128];   // [buf][d][key]   linear, swizzled content
  const int t = threadIdx.x, w = t >> 6, lane = t & 63;
  const int quad = lane >> 4, l16 = lane & 15;
  const int bx = blockIdx.x;
  const int c = bx & 7, g = bx >> 3;
  const int qt = g & 7, u = g >> 3;
  const int bh_id = u * 8 + c;
  const int b = bh_id >> 3, h = bh_id & 7;
  const size_t bh = (size_t)bh_id * 65536;
  const u16* Qb = Qp + bh;
  const u16* Kb = Kp + bh;
  const u16* Vb = Vt + bh;
  const int q0 = qt * 128 + w * 16;

  // ---- DMA source addresses (inverse-swizzled global chunks) ----
  // K: LDS slot t*16B = row r=t>>3, chunk c'=t&7; global chunk = c'^(r&7)
  const u16* kgA = Kb + (size_t)(t >> 3) * 64 + ((t & 7) ^ ((t >> 3) & 7)) * 8;
  const u16* kgB = kgA + (size_t)64 * 64;   // rows 64..127
  // V: LDS slot t*16B = row d=t>>4, chunk c'=t&15; global chunk = c'^(d&7)
  const u16* vgA = Vb + (size_t)(t >> 4) * 1024 + ((t & 15) ^ ((t >> 4) & 7)) * 8;
  const u16* vgB = vgA + (size_t)32 * 1024; // rows 32..63
  // wave-uniform LDS dests (1 KiB per wave per gl16), per buffer
  u16* ks0 = &Ks[0][0][0] + w * 512;
  u16* ks1 = &Ks[1][0][0] + w * 512;
  u16* vs0 = &Vs[0][0][0] + w * 512;
  u16* vs1 = &Vs[1][0][0] + w * 512;

  // ---- read-side swizzled base offsets (bytes), hoisted ----
  const int m7 = l16 & 7;
  const char* ksb = (const char*)&Ks[0][0][0];
  const char* vsb = (const char*)&Vs[0][0][0];
  const int kb0 = l16 * 128 + (quad ^ m7) * 16;   // logical chunk quad
  const int kb1 = kb0 ^ 64;                       // logical chunk quad+4
  int vo[4];
  #pragma unroll
  for (int ks = 0; ks < 4; ks++)                  // logical chunk 4ks+quad
    vo[ks] = l16 * 256 + ((4 * ks + quad) ^ m7) * 16;

  // Q frags (B-operand for S^T): 8 regs
  short8 qf[2];
  #pragma unroll
  for (int ks = 0; ks < 2; ks++)
    qf[ks] = *(const short8*)(Qb + (size_t)(q0 + l16) * 64 + ks * 32 + quad * 8);

  float l_ = 0.f;
  f32x4 Of[4];
  const f32x4 z4 = {0.f, 0.f, 0.f, 0.f};
  #pragma unroll
  for (int ni = 0; ni < 4; ni++) Of[ni] = z4;

  // ---- prologue: stage tile 0 into buffer 0 ----
  gl16(kgA, ks0); gl16(kgB, ks0 + 4096);
  gl16(vgA, vs0); gl16(vgB, vs0 + 4096);
  __syncthreads();   // drain prologue DMA

  #pragma unroll
  for (int kt = 0; kt < 8; kt++) {
    const int cur = kt & 1;
    // ---- issue next tile's DMA into the other buffer (hidden
    //      under this tile's compute; drained by loop-end barrier) ----
    if (kt < 7) {
      u16* kd = cur ? ks0 : ks1;
      u16* vd = cur ? vs0 : vs1;
      gl16(kgA + (kt + 1) * 8192, kd);
      gl16(kgB + (kt + 1) * 8192, kd + 4096);
      gl16(vgA + (kt + 1) * 128,  vd);
      gl16(vgB + (kt + 1) * 128,  vd + 4096);
    }
    const int co = cur * 16384;  // byte offset of current buffer

    // ---- S^T tiles + fused softmax/pack: per nt, s dies immediately.
    //      lane owns query q0+l16, keys {16nt + 4quad + r} ----
    u32 e[8], o[8];  // even-nt / odd-nt packed bf16 pairs
    __builtin_amdgcn_s_setprio(1);
    #pragma unroll
    for (int nt = 0; nt < 8; nt++) {
      short8 k0f = *(const short8*)(ksb + co + kb0 + nt * 2048);
      short8 k1f = *(const short8*)(ksb + co + kb1 + nt * 2048);
      f32x4 s = z4;
      s = MFMA16(k0f, qf[0], s);
      s = MFMA16(k1f, qf[1], s);
      float p0 = __builtin_amdgcn_exp2f(s[0]);
      float p1 = __builtin_amdgcn_exp2f(s[1]);
      float p2 = __builtin_amdgcn_exp2f(s[2]);
      float p3 = __builtin_amdgcn_exp2f(s[3]);
      l_ += (p0 + p1) + (p2 + p3);   // per-lane partial; reduced in epilogue
      const u32 lo = pkbf(p0, p1), hi = pkbf(p2, p3);
      if (nt & 1) { o[(nt >> 1) * 2] = lo; o[(nt >> 1) * 2 + 1] = hi; }
      else        { e[(nt >> 1) * 2] = lo; e[(nt >> 1) * 2 + 1] = hi; }
    }
    __builtin_amdgcn_s_setprio(0);
    // ---- cross-quad P redistribution, fully in-register, IN PLACE ----
    // pl32swap(e,o) then pl16swap: e' = {E(q0),E(q2),O(q0),O(q2)},
    //                              o' = {E(q1),E(q3),O(q1),O(q3)}
    // => A-frag(q,ks) = {e'[2ks],e'[2ks+1],o'[2ks],o'[2ks+1]}
    #pragma unroll
    for (int i = 0; i < 8; i++) {
      auto t01 = __builtin_amdgcn_permlane32_swap(e[i], o[i], false, false);
      auto xy  = __builtin_amdgcn_permlane16_swap(t01[0], t01[1], false, false);
      e[i] = xy[0]; o[i] = xy[1];
    }
    // ---- O += P V (16 MFMA), P-frags straight from registers ----
    __builtin_amdgcn_s_setprio(1);
    #pragma unroll
    for (int ks = 0; ks < 4; ks++) {
      union { short8 v; u32 u[4]; } pa;
      pa.u[0] = e[2 * ks]; pa.u[1] = e[2 * ks + 1];
      pa.u[2] = o[2 * ks]; pa.u[3] = o[2 * ks + 1];
      #pragma unroll
      for (int ni = 0; ni < 4; ni++) {
        short8 vf = *(const short8*)(vsb + co + vo[ks] + ni * 4096);
        Of[ni] = MFMA16(pa.v, vf, Of[ni]);
      }
    }
    __builtin_amdgcn_s_setprio(0);
    // ONE barrier per kt: implicit vmcnt(0) drains next-tile DMA;
    // also fences this buffer's reads before kt+1 overwrites it.
    __syncthreads();
  }
  // ---- epilogue: reduce l across quads (lanes l16,l16+16,+32,+48
  //      hold the 4 quad-partials of query l16), then normalize ----
  l_ += __shfl_xor(l_, 16);
  l_ += __shfl_xor(l_, 32);
  float lv[4];
  #pragma unroll
  for (int r = 0; r < 4; r++) lv[r] = __shfl(l_, quad * 4 + r);
  #pragma unroll
  for (int r = 0; r < 4; r++) {
    const float inv = 1.0f / lv[r];
    const int row = b * 1024 + q0 + quad * 4 + r;
    #pragma unroll
    for (int ni = 0; ni < 4; ni++)
      ATT[(size_t)row * 512 + h * 64 + ni * 16 + l16] = f2bf(Of[ni][r] * inv);
  }
}

// ============================================================
// Kernel 3: OUT = ATT(bf16) @ Wout^T + bias + ft(f32) -> f32
// Same m97-style staging as qkv_gemm.
// ============================================================
__global__ __launch_bounds__(256) void out_proj(
    const u16* __restrict__ A, const u16* __restrict__ Wt,
    const float* __restrict__ Bias, const float* __restrict__ FT,
    float* __restrict__ OUT) {
  __shared__ u16 As[128][32];
  __shared__ u16 Ws[128][32];
  const int t = threadIdx.x;
  const int bm = blockIdx.y * 128, bn = blockIdx.x * 128;
  const int w = t >> 6, lane = t & 63, quad = lane >> 4, l16 = lane & 15;
  const int mtb = (w >> 1) * 64, ntb = (w & 1) * 64;
  const int rr = lane >> 2;
  const int gch = ((lane & 3) ^ ((lane >> 3) & 3)) * 8;
  const int sw = (quad ^ ((l16 >> 1) & 3)) * 8;

  const u16* ag0 = A + (size_t)(bm + w * 16 + rr) * 512 + gch;
  const u16* ag1 = ag0 + (size_t)64 * 512;
  const u16* wg0 = Wt + (size_t)(bn + w * 16 + rr) * 512 + gch;
  const u16* wg1 = wg0 + (size_t)64 * 512;
  u16* al0 = &As[w * 16][0]; u16* al1 = &As[64 + w * 16][0];
  u16* wl0 = &Ws[w * 16][0]; u16* wl1 = &Ws[64 + w * 16][0];

  f32x4 acc[4][4];
  const f32x4 z4 = {0.f, 0.f, 0.f, 0.f};
  #pragma unroll
  for (int mi = 0; mi < 4; mi++)
    #pragma unroll
    for (int ni = 0; ni < 4; ni++) acc[mi][ni] = z4;

  for (int k0 = 0; k0 < 512; k0 += 32) {
    gl16(ag0 + k0, al0);
    gl16(ag1 + k0, al1);
    gl16(wg0 + k0, wl0);
    gl16(wg1 + k0, wl1);
    __syncthreads();
    short8 af[4], bf4[4];
    #pragma unroll
    for (int mi = 0; mi < 4; mi++)
      af[mi] = *(const short8*)&As[mtb + mi * 16 + l16][sw];
    #pragma unroll
    for (int ni = 0; ni < 4; ni++)
      bf4[ni] = *(const short8*)&Ws[ntb + ni * 16 + l16][sw];
    #pragma unroll
    for (int mi = 0; mi < 4; mi++)
      #pragma unroll
      for (int ni = 0; ni < 4; ni++)
        acc[mi][ni] = MFMA16(af[mi], bf4[ni], acc[mi][ni]);
    __syncthreads();
  }

  #pragma unroll
  for (int ni = 0; ni < 4; ni++) {
    const int g = bn + ntb + ni * 16;
    const float bias = Bias[g + l16];
    #pragma unroll
    for (int mi = 0; mi < 4; mi++) {
      const int row0 = bm + mtb + mi * 16 + quad * 4;
      #pragma unroll
      for (int r = 0; r < 4; r++) {
        const size_t idx = (size_t)(row0 + r) * 512 + g + l16;
        OUT[idx] = acc[mi][ni][r] + bias + FT[idx];
      }
    }
  }
}

// ============================================================
extern "C" void kernel_launch(void* const* d_in, const int* in_sizes, int n_in,
                              void* d_out, int out_size, void* d_ws, size_t ws_size,
                              hipStream_t stream) {
  const float* ft    = (const float*)d_in[0];  // [16][1024][512] f32
  const float* w_qkv = (const float*)d_in[1];  // [512][1536]   f32
  const float* b_qkv = (const float*)d_in[2];  // [1536]        f32
  const float* w_out = (const float*)d_in[3];  // [512][512]    f32
  const float* b_out = (const float*)d_in[4];  // [512]         f32
  float* out = (float*)d_out;                  // [16][1024][512] f32

  char* p = (char*)d_ws;
  u16* Xbf    = (u16*)(p);                              // 16,777,216
  u16* ATT    = Xbf;                                    // alias (Xbf dead)
  u16* Wqkv_t = (u16*)(p + 16777216);                   //  1,572,864
  u16* Wout_t = (u16*)(p + 18350080);                   //    524,288
  u16* Qp     = (u16*)(p + 18874368);                   // 16,777,216 (pre-scaled)
  u16* Kp     = (u16*)(p + 35651584);                   // 16,777,216
  u16* Vt     = (u16*)(p + 52428800);                   // 16,777,216 -> 69.2 MB

  conv_x     <<<4096, 256, 0, stream>>>(ft, Xbf);
  transpose_w<<<dim3(48, 16, 2), 256, 0, stream>>>(w_qkv, w_out, Wqkv_t, Wout_t);
  qkv_gemm   <<<dim3(12, 128), 256, 0, stream>>>(Xbf, Wqkv_t, b_qkv, Qp, Kp, Vt);
  attn_mfma  <<<dim3(1024), 512, 0, stream>>>(Qp, Kp, Vt, ATT);
  out_proj   <<<dim3(4, 128), 256, 0, stream>>>(ATT, Wout_t, b_out, ft, out);
}

// Round 6
// 210.726 us; speedup vs baseline: 1.5777x; 1.5777x over previous
//
#include <hip/hip_runtime.h>
#include <hip/hip_bf16.h>

using u16 = unsigned short;
using u32 = unsigned int;
typedef __attribute__((ext_vector_type(8))) short short8;  // 8 bf16 (4 VGPRs)
typedef __attribute__((ext_vector_type(4))) float f32x4;   // MFMA 16x16 C/D

#define MFMA16(A, B, C) __builtin_amdgcn_mfma_f32_16x16x32_bf16((A), (B), (C), 0, 0, 0)

// ---------- bf16 helpers ----------
__device__ __forceinline__ u16 f2bf(float f) {
  union { float f; u32 i; } v; v.f = f;
  u32 x = v.i;
  return (u16)((x + 0x7fffu + ((x >> 16) & 1u)) >> 16);  // RNE
}
__device__ __forceinline__ u32 pkbf(float a, float b) {
  union { __hip_bfloat162 h; u32 u; } v;
  v.h = __float22bfloat162_rn(make_float2(a, b));
  return v.u;
}
// async global->LDS, 16B/lane; LDS dest = wave-uniform base + lane*16
__device__ __forceinline__ void gl16(const u16* g, u16* l) {
  __builtin_amdgcn_global_load_lds(
      (const __attribute__((address_space(1))) u32*)g,
      (__attribute__((address_space(3))) u32*)l, 16, 0, 0);
}

// ============================================================
// Prep A: ft fp32 -> Xbf bf16 (16384x512)
// ============================================================
__global__ __launch_bounds__(256) void conv_x(const float* __restrict__ X,
                                              u16* __restrict__ Xbf) {
  const int i = (blockIdx.x * 256 + threadIdx.x) * 8;
  float4 a = *(const float4*)(X + i);
  float4 b = *(const float4*)(X + i + 4);
  uint4 o;
  o.x = pkbf(a.x, a.y); o.y = pkbf(a.z, a.w);
  o.z = pkbf(b.x, b.y); o.w = pkbf(b.z, b.w);
  *(uint4*)(Xbf + i) = o;
}

// ============================================================
// Prep B: transpose+convert W[512][N] fp32 -> Wt[N][512] bf16
// ============================================================
__global__ __launch_bounds__(256) void transpose_w(
    const float* __restrict__ Wq, const float* __restrict__ Wo,
    u16* __restrict__ Wqt, u16* __restrict__ Wot) {
  const int z = blockIdx.z;
  if (z == 1 && blockIdx.x >= 16) return;
  const float* src = z ? Wo : Wq;
  u16* dst = z ? Wot : Wqt;
  const int ncols = z ? 512 : 1536;
  __shared__ float tile[32][33];
  const int t = threadIdx.x;
  const int kt = blockIdx.y * 32, nt = blockIdx.x * 32;
  const int r = t >> 3, c4 = (t & 7) * 4;
  float4 v = *(const float4*)(src + (size_t)(kt + r) * ncols + nt + c4);
  tile[r][c4 + 0] = v.x; tile[r][c4 + 1] = v.y;
  tile[r][c4 + 2] = v.z; tile[r][c4 + 3] = v.w;
  __syncthreads();
  uint2 p = make_uint2(pkbf(tile[c4 + 0][r], tile[c4 + 1][r]),
                       pkbf(tile[c4 + 2][r], tile[c4 + 3][r]));
  *(uint2*)(dst + (size_t)(nt + r) * 512 + kt + c4) = p;
}

// ============================================================
// Kernel 1: QKV GEMM, m97-style staging with global-pointer XOR
// swizzle. Q pre-scaled by 0.125*log2(e) so attention softmax can
// use native v_exp_f32 (2^x) directly (softmax is shift-invariant).
// -> Qp[b][h][n][64]*SCALE*log2e, Kp[b][h][n][64], Vt[b][h][64][n]
// ============================================================
__global__ __launch_bounds__(256) void qkv_gemm(
    const u16* __restrict__ Xbf, const u16* __restrict__ Wt,
    const float* __restrict__ Bias,
    u16* __restrict__ Qp, u16* __restrict__ Kp, u16* __restrict__ Vt) {
  __shared__ u16 Xs[128][32];  // [m][k] unpadded, 64 B rows
  __shared__ u16 Ws[128][32];  // [n][k]
  const int t = threadIdx.x;
  const int bm = blockIdx.y * 128, bn = blockIdx.x * 128;
  const int w = t >> 6, lane = t & 63, quad = lane >> 4, l16 = lane & 15;
  const int mtb = (w >> 1) * 64, ntb = (w & 1) * 64;
  const int rr = lane >> 2;                                  // row in 16-row group
  const int gch = ((lane & 3) ^ ((lane >> 3) & 3)) * 8;      // swizzled global chunk
  const int sw = (quad ^ ((l16 >> 1) & 3)) * 8;              // frag-read chunk

  const u16* xg0 = Xbf + (size_t)(bm + w * 16 + rr) * 512 + gch;
  const u16* xg1 = xg0 + (size_t)64 * 512;
  const u16* wg0 = Wt + (size_t)(bn + w * 16 + rr) * 512 + gch;
  const u16* wg1 = wg0 + (size_t)64 * 512;
  u16* xl0 = &Xs[w * 16][0]; u16* xl1 = &Xs[64 + w * 16][0];
  u16* wl0 = &Ws[w * 16][0]; u16* wl1 = &Ws[64 + w * 16][0];

  f32x4 acc[4][4];
  const f32x4 z4 = {0.f, 0.f, 0.f, 0.f};
  #pragma unroll
  for (int mi = 0; mi < 4; mi++)
    #pragma unroll
    for (int ni = 0; ni < 4; ni++) acc[mi][ni] = z4;

  for (int k0 = 0; k0 < 512; k0 += 32) {
    gl16(xg0 + k0, xl0);
    gl16(xg1 + k0, xl1);
    gl16(wg0 + k0, wl0);
    gl16(wg1 + k0, wl1);
    __syncthreads();  // drain DMA (vmcnt0) + visibility
    short8 af[4], bf4[4];
    #pragma unroll
    for (int mi = 0; mi < 4; mi++)
      af[mi] = *(const short8*)&Xs[mtb + mi * 16 + l16][sw];
    #pragma unroll
    for (int ni = 0; ni < 4; ni++)
      bf4[ni] = *(const short8*)&Ws[ntb + ni * 16 + l16][sw];
    #pragma unroll
    for (int mi = 0; mi < 4; mi++)
      #pragma unroll
      for (int ni = 0; ni < 4; ni++)
        acc[mi][ni] = MFMA16(af[mi], bf4[ni], acc[mi][ni]);
    __syncthreads();  // reads done before next DMA overwrites
  }

  // epilogue: C-layout (row=quad*4+r, col=l16) -> packed Q/K/V
  #pragma unroll
  for (int ni = 0; ni < 4; ni++) {
    const int g = bn + ntb + ni * 16;
    const int h = g / 192, rm = g % 192;
    const int type = rm >> 6, dbase = rm & 63;
    const float bias = Bias[g + l16];
    // fold softmax scale AND log2(e) into Q so attn uses exp2 natively
    const float qsc = (type == 0) ? 0.125f * 1.44269504088896340736f : 1.0f;
    #pragma unroll
    for (int mi = 0; mi < 4; mi++) {
      const int row0 = bm + mtb + mi * 16 + quad * 4;
      const int b = row0 >> 10, n0 = row0 & 1023;
      const size_t bh = (size_t)(b * 8 + h) * 65536;
      if (type == 2) {  // V -> Vt[b][h][d][n]
        uint2 p = make_uint2(pkbf(acc[mi][ni][0] + bias, acc[mi][ni][1] + bias),
                             pkbf(acc[mi][ni][2] + bias, acc[mi][ni][3] + bias));
        *(uint2*)(Vt + bh + (size_t)(dbase + l16) * 1024 + n0) = p;
      } else {
        u16* dst = (type ? Kp : Qp) + bh;
        #pragma unroll
        for (int r = 0; r < 4; r++)
          dst[(size_t)(n0 + r) * 64 + dbase + l16] =
              f2bf((acc[mi][ni][r] + bias) * qsc);
      }
    }
  }
}

// ============================================================
// Kernel 2 v9: flash attention = v7 (DMA staging, pre-swizzled
// global source, no P LDS, no online-max) + DOUBLE-BUFFER as a
// NON-UNROLLED runtime loop (T3 minimum 2-phase recipe), no setprio.
// v8's regression was diagnosed as unroll-induced live-range
// extension -> per-iteration scratch spill (WRITE_SIZE 16->360 MB).
// Runtime loop keeps loop-carried pressure explicit (~70 VGPR peak).
// Per kt: issue next tile's 4 gl16 into buf^1 -> compute buf ->
// ONE __syncthreads() (implicit vmcnt(0) drains a DMA that had the
// whole 32-MFMA+softmax phase to land).
// Race check: buf^1 written at kt was last read at kt-1, fenced by
// the kt-1 end barrier; buf's reads are fenced by the kt barrier
// before kt+1 overwrites it.
// ============================================================
__global__ __launch_bounds__(512, 4) void attn_mfma(
    const u16* __restrict__ Qp, const u16* __restrict__ Kp,
    const u16* __restrict__ Vt, u16* __restrict__ ATT) {
  __shared__ u16 Ks[2][128][64];   // [buf][key][d]   linear, swizzled content
  __shared__ u16 Vs[2][64][128];   // [buf][d][key]   linear, swizzled content
  const int t = threadIdx.x, w = t >> 6, lane = t & 63;
  const int quad = lane >> 4, l16 = lane & 15;
  const int bx = blockIdx.x;
  const int c = bx & 7, g = bx >> 3;
  const int qt = g & 7, u = g >> 3;
  const int bh_id = u * 8 + c;
  const int b = bh_id >> 3, h = bh_id & 7;
  const size_t bh = (size_t)bh_id * 65536;
  const u16* Qb = Qp + bh;
  const u16* Kb = Kp + bh;
  const u16* Vb = Vt + bh;
  const int q0 = qt * 128 + w * 16;

  // ---- DMA source addresses (inverse-swizzled global chunks) ----
  // K: LDS slot t*16B = row r=t>>3, chunk c'=t&7; global chunk = c'^(r&7)
  const u16* kgA = Kb + (size_t)(t >> 3) * 64 + ((t & 7) ^ ((t >> 3) & 7)) * 8;
  const u16* kgB = kgA + (size_t)64 * 64;   // rows 64..127
  // V: LDS slot t*16B = row d=t>>4, chunk c'=t&15; global chunk = c'^(d&7)
  const u16* vgA = Vb + (size_t)(t >> 4) * 1024 + ((t & 15) ^ ((t >> 4) & 7)) * 8;
  const u16* vgB = vgA + (size_t)32 * 1024; // rows 32..63
  // wave-uniform LDS dests (1 KiB per wave per gl16), per buffer
  u16* ks0 = &Ks[0][0][0] + w * 512;
  u16* ks1 = &Ks[1][0][0] + w * 512;
  u16* vs0 = &Vs[0][0][0] + w * 512;
  u16* vs1 = &Vs[1][0][0] + w * 512;

  // ---- read-side swizzled base offsets (bytes), hoisted ----
  const int m7 = l16 & 7;
  const char* ksb = (const char*)&Ks[0][0][0];
  const char* vsb = (const char*)&Vs[0][0][0];
  const int kb0 = l16 * 128 + (quad ^ m7) * 16;   // logical chunk quad
  const int kb1 = kb0 ^ 64;                       // logical chunk quad+4
  int vo[4];
  #pragma unroll
  for (int ks = 0; ks < 4; ks++)                  // logical chunk 4ks+quad
    vo[ks] = l16 * 256 + ((4 * ks + quad) ^ m7) * 16;

  // Q frags (B-operand for S^T): 8 regs
  short8 qf[2];
  #pragma unroll
  for (int ks = 0; ks < 2; ks++)
    qf[ks] = *(const short8*)(Qb + (size_t)(q0 + l16) * 64 + ks * 32 + quad * 8);

  float l_ = 0.f;
  f32x4 Of[4];
  const f32x4 z4 = {0.f, 0.f, 0.f, 0.f};
  #pragma unroll
  for (int ni = 0; ni < 4; ni++) Of[ni] = z4;

  // ---- prologue: stage tile 0 into buffer 0 ----
  gl16(kgA, ks0); gl16(kgB, ks0 + 4096);
  gl16(vgA, vs0); gl16(vgB, vs0 + 4096);
  __syncthreads();   // drain prologue DMA

  for (int kt = 0; kt < 8; ++kt) {   // NOT unrolled (v8 spill lesson)
    const int cur = kt & 1;
    // ---- issue next tile's DMA into the other buffer (hidden
    //      under this tile's compute; drained by loop-end barrier) ----
    if (kt < 7) {
      u16* kd = cur ? ks0 : ks1;
      u16* vd = cur ? vs0 : vs1;
      gl16(kgA + (kt + 1) * 8192, kd);
      gl16(kgB + (kt + 1) * 8192, kd + 4096);
      gl16(vgA + (kt + 1) * 128,  vd);
      gl16(vgB + (kt + 1) * 128,  vd + 4096);
    }
    const int co = cur << 14;  // byte offset of current buffer (16384)

    // ---- S^T tiles + fused softmax/pack: per nt, s dies immediately.
    //      lane owns query q0+l16, keys {16nt + 4quad + r} ----
    u32 e[8], o[8];  // even-nt / odd-nt packed bf16 pairs
    #pragma unroll
    for (int nt = 0; nt < 8; nt++) {
      short8 k0f = *(const short8*)(ksb + co + kb0 + nt * 2048);
      short8 k1f = *(const short8*)(ksb + co + kb1 + nt * 2048);
      f32x4 s = z4;
      s = MFMA16(k0f, qf[0], s);
      s = MFMA16(k1f, qf[1], s);
      float p0 = __builtin_amdgcn_exp2f(s[0]);
      float p1 = __builtin_amdgcn_exp2f(s[1]);
      float p2 = __builtin_amdgcn_exp2f(s[2]);
      float p3 = __builtin_amdgcn_exp2f(s[3]);
      l_ += (p0 + p1) + (p2 + p3);   // per-lane partial; reduced in epilogue
      const u32 lo = pkbf(p0, p1), hi = pkbf(p2, p3);
      if (nt & 1) { o[(nt >> 1) * 2] = lo; o[(nt >> 1) * 2 + 1] = hi; }
      else        { e[(nt >> 1) * 2] = lo; e[(nt >> 1) * 2 + 1] = hi; }
    }
    // ---- cross-quad P redistribution, fully in-register, IN PLACE ----
    // pl32swap(e,o) then pl16swap: e' = {E(q0),E(q2),O(q0),O(q2)},
    //                              o' = {E(q1),E(q3),O(q1),O(q3)}
    // => A-frag(q,ks) = {e'[2ks],e'[2ks+1],o'[2ks],o'[2ks+1]}
    #pragma unroll
    for (int i = 0; i < 8; i++) {
      auto t01 = __builtin_amdgcn_permlane32_swap(e[i], o[i], false, false);
      auto xy  = __builtin_amdgcn_permlane16_swap(t01[0], t01[1], false, false);
      e[i] = xy[0]; o[i] = xy[1];
    }
    // ---- O += P V (16 MFMA), P-frags straight from registers ----
    #pragma unroll
    for (int ks = 0; ks < 4; ks++) {
      union { short8 v; u32 u[4]; } pa;
      pa.u[0] = e[2 * ks]; pa.u[1] = e[2 * ks + 1];
      pa.u[2] = o[2 * ks]; pa.u[3] = o[2 * ks + 1];
      #pragma unroll
      for (int ni = 0; ni < 4; ni++) {
        short8 vf = *(const short8*)(vsb + co + vo[ks] + ni * 4096);
        Of[ni] = MFMA16(pa.v, vf, Of[ni]);
      }
    }
    // ONE barrier per kt: implicit vmcnt(0) drains next-tile DMA;
    // also fences this buffer's reads before kt+1 overwrites it.
    __syncthreads();
  }
  // ---- epilogue: reduce l across quads (lanes l16,l16+16,+32,+48
  //      hold the 4 quad-partials of query l16), then normalize ----
  l_ += __shfl_xor(l_, 16);
  l_ += __shfl_xor(l_, 32);
  float lv[4];
  #pragma unroll
  for (int r = 0; r < 4; r++) lv[r] = __shfl(l_, quad * 4 + r);
  #pragma unroll
  for (int r = 0; r < 4; r++) {
    const float inv = 1.0f / lv[r];
    const int row = b * 1024 + q0 + quad * 4 + r;
    #pragma unroll
    for (int ni = 0; ni < 4; ni++)
      ATT[(size_t)row * 512 + h * 64 + ni * 16 + l16] = f2bf(Of[ni][r] * inv);
  }
}

// ============================================================
// Kernel 3: OUT = ATT(bf16) @ Wout^T + bias + ft(f32) -> f32
// Same m97-style staging as qkv_gemm.
// ============================================================
__global__ __launch_bounds__(256) void out_proj(
    const u16* __restrict__ A, const u16* __restrict__ Wt,
    const float* __restrict__ Bias, const float* __restrict__ FT,
    float* __restrict__ OUT) {
  __shared__ u16 As[128][32];
  __shared__ u16 Ws[128][32];
  const int t = threadIdx.x;
  const int bm = blockIdx.y * 128, bn = blockIdx.x * 128;
  const int w = t >> 6, lane = t & 63, quad = lane >> 4, l16 = lane & 15;
  const int mtb = (w >> 1) * 64, ntb = (w & 1) * 64;
  const int rr = lane >> 2;
  const int gch = ((lane & 3) ^ ((lane >> 3) & 3)) * 8;
  const int sw = (quad ^ ((l16 >> 1) & 3)) * 8;

  const u16* ag0 = A + (size_t)(bm + w * 16 + rr) * 512 + gch;
  const u16* ag1 = ag0 + (size_t)64 * 512;
  const u16* wg0 = Wt + (size_t)(bn + w * 16 + rr) * 512 + gch;
  const u16* wg1 = wg0 + (size_t)64 * 512;
  u16* al0 = &As[w * 16][0]; u16* al1 = &As[64 + w * 16][0];
  u16* wl0 = &Ws[w * 16][0]; u16* wl1 = &Ws[64 + w * 16][0];

  f32x4 acc[4][4];
  const f32x4 z4 = {0.f, 0.f, 0.f, 0.f};
  #pragma unroll
  for (int mi = 0; mi < 4; mi++)
    #pragma unroll
    for (int ni = 0; ni < 4; ni++) acc[mi][ni] = z4;

  for (int k0 = 0; k0 < 512; k0 += 32) {
    gl16(ag0 + k0, al0);
    gl16(ag1 + k0, al1);
    gl16(wg0 + k0, wl0);
    gl16(wg1 + k0, wl1);
    __syncthreads();
    short8 af[4], bf4[4];
    #pragma unroll
    for (int mi = 0; mi < 4; mi++)
      af[mi] = *(const short8*)&As[mtb + mi * 16 + l16][sw];
    #pragma unroll
    for (int ni = 0; ni < 4; ni++)
      bf4[ni] = *(const short8*)&Ws[ntb + ni * 16 + l16][sw];
    #pragma unroll
    for (int mi = 0; mi < 4; mi++)
      #pragma unroll
      for (int ni = 0; ni < 4; ni++)
        acc[mi][ni] = MFMA16(af[mi], bf4[ni], acc[mi][ni]);
    __syncthreads();
  }

  #pragma unroll
  for (int ni = 0; ni < 4; ni++) {
    const int g = bn + ntb + ni * 16;
    const float bias = Bias[g + l16];
    #pragma unroll
    for (int mi = 0; mi < 4; mi++) {
      const int row0 = bm + mtb + mi * 16 + quad * 4;
      #pragma unroll
      for (int r = 0; r < 4; r++) {
        const size_t idx = (size_t)(row0 + r) * 512 + g + l16;
        OUT[idx] = acc[mi][ni][r] + bias + FT[idx];
      }
    }
  }
}

// ============================================================
extern "C" void kernel_launch(void* const* d_in, const int* in_sizes, int n_in,
                              void* d_out, int out_size, void* d_ws, size_t ws_size,
                              hipStream_t stream) {
  const float* ft    = (const float*)d_in[0];  // [16][1024][512] f32
  const float* w_qkv = (const float*)d_in[1];  // [512][1536]   f32
  const float* b_qkv = (const float*)d_in[2];  // [1536]        f32
  const float* w_out = (const float*)d_in[3];  // [512][512]    f32
  const float* b_out = (const float*)d_in[4];  // [512]         f32
  float* out = (float*)d_out;                  // [16][1024][512] f32

  char* p = (char*)d_ws;
  u16* Xbf    = (u16*)(p);                              // 16,777,216
  u16* ATT    = Xbf;                                    // alias (Xbf dead)
  u16* Wqkv_t = (u16*)(p + 16777216);                   //  1,572,864
  u16* Wout_t = (u16*)(p + 18350080);                   //    524,288
  u16* Qp     = (u16*)(p + 18874368);                   // 16,777,216 (pre-scaled)
  u16* Kp     = (u16*)(p + 35651584);                   // 16,777,216
  u16* Vt     = (u16*)(p + 52428800);                   // 16,777,216 -> 69.2 MB

  conv_x     <<<4096, 256, 0, stream>>>(ft, Xbf);
  transpose_w<<<dim3(48, 16, 2), 256, 0, stream>>>(w_qkv, w_out, Wqkv_t, Wout_t);
  qkv_gemm   <<<dim3(12, 128), 256, 0, stream>>>(Xbf, Wqkv_t, b_qkv, Qp, Kp, Vt);
  attn_mfma  <<<dim3(1024), 512, 0, stream>>>(Qp, Kp, Vt, ATT);
  out_proj   <<<dim3(4, 128), 256, 0, stream>>>(ATT, Wout_t, b_out, ft, out);
}

// Round 7
// 202.119 us; speedup vs baseline: 1.6449x; 1.0426x over previous
//
#include <hip/hip_runtime.h>
#include <hip/hip_bf16.h>

using u16 = unsigned short;
using u32 = unsigned int;
typedef __attribute__((ext_vector_type(8))) short short8;  // 8 bf16 (4 VGPRs)
typedef __attribute__((ext_vector_type(4))) float f32x4;   // MFMA 16x16 C/D

#define MFMA16(A, B, C) __builtin_amdgcn_mfma_f32_16x16x32_bf16((A), (B), (C), 0, 0, 0)

// ---------- bf16 helpers ----------
__device__ __forceinline__ u16 f2bf(float f) {
  union { float f; u32 i; } v; v.f = f;
  u32 x = v.i;
  return (u16)((x + 0x7fffu + ((x >> 16) & 1u)) >> 16);  // RNE
}
__device__ __forceinline__ u32 pkbf(float a, float b) {
  union { __hip_bfloat162 h; u32 u; } v;
  v.h = __float22bfloat162_rn(make_float2(a, b));
  return v.u;
}
// async global->LDS, 16B/lane; LDS dest = wave-uniform base + lane*16
__device__ __forceinline__ void gl16(const u16* g, u16* l) {
  __builtin_amdgcn_global_load_lds(
      (const __attribute__((address_space(1))) u32*)g,
      (__attribute__((address_space(3))) u32*)l, 16, 0, 0);
}

// ============================================================
// Prep A: ft fp32 -> Xbf bf16 (16384x512)
// ============================================================
__global__ __launch_bounds__(256) void conv_x(const float* __restrict__ X,
                                              u16* __restrict__ Xbf) {
  const int i = (blockIdx.x * 256 + threadIdx.x) * 8;
  float4 a = *(const float4*)(X + i);
  float4 b = *(const float4*)(X + i + 4);
  uint4 o;
  o.x = pkbf(a.x, a.y); o.y = pkbf(a.z, a.w);
  o.z = pkbf(b.x, b.y); o.w = pkbf(b.z, b.w);
  *(uint4*)(Xbf + i) = o;
}

// ============================================================
// Prep B: transpose+convert W[512][N] fp32 -> Wt[N][512] bf16
// ============================================================
__global__ __launch_bounds__(256) void transpose_w(
    const float* __restrict__ Wq, const float* __restrict__ Wo,
    u16* __restrict__ Wqt, u16* __restrict__ Wot) {
  const int z = blockIdx.z;
  if (z == 1 && blockIdx.x >= 16) return;
  const float* src = z ? Wo : Wq;
  u16* dst = z ? Wot : Wqt;
  const int ncols = z ? 512 : 1536;
  __shared__ float tile[32][33];
  const int t = threadIdx.x;
  const int kt = blockIdx.y * 32, nt = blockIdx.x * 32;
  const int r = t >> 3, c4 = (t & 7) * 4;
  float4 v = *(const float4*)(src + (size_t)(kt + r) * ncols + nt + c4);
  tile[r][c4 + 0] = v.x; tile[r][c4 + 1] = v.y;
  tile[r][c4 + 2] = v.z; tile[r][c4 + 3] = v.w;
  __syncthreads();
  uint2 p = make_uint2(pkbf(tile[c4 + 0][r], tile[c4 + 1][r]),
                       pkbf(tile[c4 + 2][r], tile[c4 + 3][r]));
  *(uint2*)(dst + (size_t)(nt + r) * 512 + kt + c4) = p;
}

// ============================================================
// Kernel 1 v2: QKV GEMM, m97-style staging + 2-phase DOUBLE-BUFFER
// (non-unrolled runtime K-loop; same T3-minimum schedule that fixed
// attn). Per step: issue next tile's DMA into buf^1 -> compute buf
// (8 ds_read_b128 + 16 MFMA) -> ONE barrier (implicit vmcnt(0)
// drains a DMA that had the whole compute phase to land).
// Q pre-scaled by 0.125*log2(e) (softmax shift-invariance).
// -> Qp[b][h][n][64]*SCALE*log2e, Kp[b][h][n][64], Vt[b][h][64][n]
// ============================================================
__global__ __launch_bounds__(256) void qkv_gemm(
    const u16* __restrict__ Xbf, const u16* __restrict__ Wt,
    const float* __restrict__ Bias,
    u16* __restrict__ Qp, u16* __restrict__ Kp, u16* __restrict__ Vt) {
  __shared__ u16 Xs[2][128][32];  // [buf][m][k] unpadded, 64 B rows
  __shared__ u16 Ws[2][128][32];  // [buf][n][k]
  const int t = threadIdx.x;
  const int bm = blockIdx.y * 128, bn = blockIdx.x * 128;
  const int w = t >> 6, lane = t & 63, quad = lane >> 4, l16 = lane & 15;
  const int mtb = (w >> 1) * 64, ntb = (w & 1) * 64;
  const int rr = lane >> 2;                                  // row in 16-row group
  const int gch = ((lane & 3) ^ ((lane >> 3) & 3)) * 8;      // swizzled global chunk
  const int sw = (quad ^ ((l16 >> 1) & 3)) * 8;              // frag-read chunk

  const u16* xg0 = Xbf + (size_t)(bm + w * 16 + rr) * 512 + gch;
  const u16* xg1 = xg0 + (size_t)64 * 512;
  const u16* wg0 = Wt + (size_t)(bn + w * 16 + rr) * 512 + gch;
  const u16* wg1 = wg0 + (size_t)64 * 512;
  // per-buffer wave-uniform LDS dests
  u16* xl0[2] = {&Xs[0][w * 16][0], &Xs[1][w * 16][0]};
  u16* wl0[2] = {&Ws[0][w * 16][0], &Ws[1][w * 16][0]};

  f32x4 acc[4][4];
  const f32x4 z4 = {0.f, 0.f, 0.f, 0.f};
  #pragma unroll
  for (int mi = 0; mi < 4; mi++)
    #pragma unroll
    for (int ni = 0; ni < 4; ni++) acc[mi][ni] = z4;

  // ---- prologue: stage K-step 0 into buffer 0 ----
  gl16(xg0, xl0[0]); gl16(xg1, xl0[0] + 2048);
  gl16(wg0, wl0[0]); gl16(wg1, wl0[0] + 2048);
  __syncthreads();

  for (int k0 = 0; k0 < 512; k0 += 32) {   // runtime loop (v8 spill lesson)
    const int cur = (k0 >> 5) & 1;
    if (k0 < 480) {                        // issue next step into buf^1
      const int nxt = cur ^ 1, kn = k0 + 32;
      gl16(xg0 + kn, xl0[nxt]); gl16(xg1 + kn, xl0[nxt] + 2048);
      gl16(wg0 + kn, wl0[nxt]); gl16(wg1 + kn, wl0[nxt] + 2048);
    }
    short8 af[4], bf4[4];
    #pragma unroll
    for (int mi = 0; mi < 4; mi++)
      af[mi] = *(const short8*)&Xs[cur][mtb + mi * 16 + l16][sw];
    #pragma unroll
    for (int ni = 0; ni < 4; ni++)
      bf4[ni] = *(const short8*)&Ws[cur][ntb + ni * 16 + l16][sw];
    #pragma unroll
    for (int mi = 0; mi < 4; mi++)
      #pragma unroll
      for (int ni = 0; ni < 4; ni++)
        acc[mi][ni] = MFMA16(af[mi], bf4[ni], acc[mi][ni]);
    // ONE barrier: drains next-step DMA (had whole compute to land)
    // and fences this buffer's reads before step+2 overwrites it.
    __syncthreads();
  }

  // epilogue: C-layout (row=quad*4+r, col=l16) -> packed Q/K/V
  #pragma unroll
  for (int ni = 0; ni < 4; ni++) {
    const int g = bn + ntb + ni * 16;
    const int h = g / 192, rm = g % 192;
    const int type = rm >> 6, dbase = rm & 63;
    const float bias = Bias[g + l16];
    // fold softmax scale AND log2(e) into Q so attn uses exp2 natively
    const float qsc = (type == 0) ? 0.125f * 1.44269504088896340736f : 1.0f;
    #pragma unroll
    for (int mi = 0; mi < 4; mi++) {
      const int row0 = bm + mtb + mi * 16 + quad * 4;
      const int b = row0 >> 10, n0 = row0 & 1023;
      const size_t bh = (size_t)(b * 8 + h) * 65536;
      if (type == 2) {  // V -> Vt[b][h][d][n]
        uint2 p = make_uint2(pkbf(acc[mi][ni][0] + bias, acc[mi][ni][1] + bias),
                             pkbf(acc[mi][ni][2] + bias, acc[mi][ni][3] + bias));
        *(uint2*)(Vt + bh + (size_t)(dbase + l16) * 1024 + n0) = p;
      } else {
        u16* dst = (type ? Kp : Qp) + bh;
        #pragma unroll
        for (int r = 0; r < 4; r++)
          dst[(size_t)(n0 + r) * 64 + dbase + l16] =
              f2bf((acc[mi][ni][r] + bias) * qsc);
      }
    }
  }
}

// ============================================================
// Kernel 2 v9: flash attention = v7 (DMA staging, pre-swizzled
// global source, no P LDS, no online-max) + DOUBLE-BUFFER as a
// NON-UNROLLED runtime loop (T3 minimum 2-phase recipe), no setprio.
// ============================================================
__global__ __launch_bounds__(512, 4) void attn_mfma(
    const u16* __restrict__ Qp, const u16* __restrict__ Kp,
    const u16* __restrict__ Vt, u16* __restrict__ ATT) {
  __shared__ u16 Ks[2][128][64];   // [buf][key][d]   linear, swizzled content
  __shared__ u16 Vs[2][64][128];   // [buf][d][key]   linear, swizzled content
  const int t = threadIdx.x, w = t >> 6, lane = t & 63;
  const int quad = lane >> 4, l16 = lane & 15;
  const int bx = blockIdx.x;
  const int c = bx & 7, g = bx >> 3;
  const int qt = g & 7, u = g >> 3;
  const int bh_id = u * 8 + c;
  const int b = bh_id >> 3, h = bh_id & 7;
  const size_t bh = (size_t)bh_id * 65536;
  const u16* Qb = Qp + bh;
  const u16* Kb = Kp + bh;
  const u16* Vb = Vt + bh;
  const int q0 = qt * 128 + w * 16;

  // ---- DMA source addresses (inverse-swizzled global chunks) ----
  const u16* kgA = Kb + (size_t)(t >> 3) * 64 + ((t & 7) ^ ((t >> 3) & 7)) * 8;
  const u16* kgB = kgA + (size_t)64 * 64;   // rows 64..127
  const u16* vgA = Vb + (size_t)(t >> 4) * 1024 + ((t & 15) ^ ((t >> 4) & 7)) * 8;
  const u16* vgB = vgA + (size_t)32 * 1024; // rows 32..63
  // wave-uniform LDS dests (1 KiB per wave per gl16), per buffer
  u16* ks0 = &Ks[0][0][0] + w * 512;
  u16* ks1 = &Ks[1][0][0] + w * 512;
  u16* vs0 = &Vs[0][0][0] + w * 512;
  u16* vs1 = &Vs[1][0][0] + w * 512;

  // ---- read-side swizzled base offsets (bytes), hoisted ----
  const int m7 = l16 & 7;
  const char* ksb = (const char*)&Ks[0][0][0];
  const char* vsb = (const char*)&Vs[0][0][0];
  const int kb0 = l16 * 128 + (quad ^ m7) * 16;   // logical chunk quad
  const int kb1 = kb0 ^ 64;                       // logical chunk quad+4
  int vo[4];
  #pragma unroll
  for (int ks = 0; ks < 4; ks++)                  // logical chunk 4ks+quad
    vo[ks] = l16 * 256 + ((4 * ks + quad) ^ m7) * 16;

  // Q frags (B-operand for S^T): 8 regs
  short8 qf[2];
  #pragma unroll
  for (int ks = 0; ks < 2; ks++)
    qf[ks] = *(const short8*)(Qb + (size_t)(q0 + l16) * 64 + ks * 32 + quad * 8);

  float l_ = 0.f;
  f32x4 Of[4];
  const f32x4 z4 = {0.f, 0.f, 0.f, 0.f};
  #pragma unroll
  for (int ni = 0; ni < 4; ni++) Of[ni] = z4;

  // ---- prologue: stage tile 0 into buffer 0 ----
  gl16(kgA, ks0); gl16(kgB, ks0 + 4096);
  gl16(vgA, vs0); gl16(vgB, vs0 + 4096);
  __syncthreads();   // drain prologue DMA

  for (int kt = 0; kt < 8; ++kt) {   // NOT unrolled (v8 spill lesson)
    const int cur = kt & 1;
    if (kt < 7) {
      u16* kd = cur ? ks0 : ks1;
      u16* vd = cur ? vs0 : vs1;
      gl16(kgA + (kt + 1) * 8192, kd);
      gl16(kgB + (kt + 1) * 8192, kd + 4096);
      gl16(vgA + (kt + 1) * 128,  vd);
      gl16(vgB + (kt + 1) * 128,  vd + 4096);
    }
    const int co = cur << 14;  // byte offset of current buffer (16384)

    // ---- S^T tiles + fused softmax/pack ----
    u32 e[8], o[8];  // even-nt / odd-nt packed bf16 pairs
    #pragma unroll
    for (int nt = 0; nt < 8; nt++) {
      short8 k0f = *(const short8*)(ksb + co + kb0 + nt * 2048);
      short8 k1f = *(const short8*)(ksb + co + kb1 + nt * 2048);
      f32x4 s = z4;
      s = MFMA16(k0f, qf[0], s);
      s = MFMA16(k1f, qf[1], s);
      float p0 = __builtin_amdgcn_exp2f(s[0]);
      float p1 = __builtin_amdgcn_exp2f(s[1]);
      float p2 = __builtin_amdgcn_exp2f(s[2]);
      float p3 = __builtin_amdgcn_exp2f(s[3]);
      l_ += (p0 + p1) + (p2 + p3);   // per-lane partial; reduced in epilogue
      const u32 lo = pkbf(p0, p1), hi = pkbf(p2, p3);
      if (nt & 1) { o[(nt >> 1) * 2] = lo; o[(nt >> 1) * 2 + 1] = hi; }
      else        { e[(nt >> 1) * 2] = lo; e[(nt >> 1) * 2 + 1] = hi; }
    }
    // ---- cross-quad P redistribution, in-register, IN PLACE ----
    #pragma unroll
    for (int i = 0; i < 8; i++) {
      auto t01 = __builtin_amdgcn_permlane32_swap(e[i], o[i], false, false);
      auto xy  = __builtin_amdgcn_permlane16_swap(t01[0], t01[1], false, false);
      e[i] = xy[0]; o[i] = xy[1];
    }
    // ---- O += P V (16 MFMA), P-frags straight from registers ----
    #pragma unroll
    for (int ks = 0; ks < 4; ks++) {
      union { short8 v; u32 u[4]; } pa;
      pa.u[0] = e[2 * ks]; pa.u[1] = e[2 * ks + 1];
      pa.u[2] = o[2 * ks]; pa.u[3] = o[2 * ks + 1];
      #pragma unroll
      for (int ni = 0; ni < 4; ni++) {
        short8 vf = *(const short8*)(vsb + co + vo[ks] + ni * 4096);
        Of[ni] = MFMA16(pa.v, vf, Of[ni]);
      }
    }
    __syncthreads();
  }
  // ---- epilogue ----
  l_ += __shfl_xor(l_, 16);
  l_ += __shfl_xor(l_, 32);
  float lv[4];
  #pragma unroll
  for (int r = 0; r < 4; r++) lv[r] = __shfl(l_, quad * 4 + r);
  #pragma unroll
  for (int r = 0; r < 4; r++) {
    const float inv = 1.0f / lv[r];
    const int row = b * 1024 + q0 + quad * 4 + r;
    #pragma unroll
    for (int ni = 0; ni < 4; ni++)
      ATT[(size_t)row * 512 + h * 64 + ni * 16 + l16] = f2bf(Of[ni][r] * inv);
  }
}

// ============================================================
// Kernel 3 v2: OUT = ATT(bf16) @ Wout^T + bias + ft(f32) -> f32
// Same 2-phase double-buffered staging as qkv_gemm v2.
// ============================================================
__global__ __launch_bounds__(256) void out_proj(
    const u16* __restrict__ A, const u16* __restrict__ Wt,
    const float* __restrict__ Bias, const float* __restrict__ FT,
    float* __restrict__ OUT) {
  __shared__ u16 As[2][128][32];
  __shared__ u16 Ws[2][128][32];
  const int t = threadIdx.x;
  const int bm = blockIdx.y * 128, bn = blockIdx.x * 128;
  const int w = t >> 6, lane = t & 63, quad = lane >> 4, l16 = lane & 15;
  const int mtb = (w >> 1) * 64, ntb = (w & 1) * 64;
  const int rr = lane >> 2;
  const int gch = ((lane & 3) ^ ((lane >> 3) & 3)) * 8;
  const int sw = (quad ^ ((l16 >> 1) & 3)) * 8;

  const u16* ag0 = A + (size_t)(bm + w * 16 + rr) * 512 + gch;
  const u16* ag1 = ag0 + (size_t)64 * 512;
  const u16* wg0 = Wt + (size_t)(bn + w * 16 + rr) * 512 + gch;
  const u16* wg1 = wg0 + (size_t)64 * 512;
  u16* al0[2] = {&As[0][w * 16][0], &As[1][w * 16][0]};
  u16* wl0[2] = {&Ws[0][w * 16][0], &Ws[1][w * 16][0]};

  f32x4 acc[4][4];
  const f32x4 z4 = {0.f, 0.f, 0.f, 0.f};
  #pragma unroll
  for (int mi = 0; mi < 4; mi++)
    #pragma unroll
    for (int ni = 0; ni < 4; ni++) acc[mi][ni] = z4;

  // ---- prologue: stage K-step 0 into buffer 0 ----
  gl16(ag0, al0[0]); gl16(ag1, al0[0] + 2048);
  gl16(wg0, wl0[0]); gl16(wg1, wl0[0] + 2048);
  __syncthreads();

  for (int k0 = 0; k0 < 512; k0 += 32) {   // runtime loop
    const int cur = (k0 >> 5) & 1;
    if (k0 < 480) {
      const int nxt = cur ^ 1, kn = k0 + 32;
      gl16(ag0 + kn, al0[nxt]); gl16(ag1 + kn, al0[nxt] + 2048);
      gl16(wg0 + kn, wl0[nxt]); gl16(wg1 + kn, wl0[nxt] + 2048);
    }
    short8 af[4], bf4[4];
    #pragma unroll
    for (int mi = 0; mi < 4; mi++)
      af[mi] = *(const short8*)&As[cur][mtb + mi * 16 + l16][sw];
    #pragma unroll
    for (int ni = 0; ni < 4; ni++)
      bf4[ni] = *(const short8*)&Ws[cur][ntb + ni * 16 + l16][sw];
    #pragma unroll
    for (int mi = 0; mi < 4; mi++)
      #pragma unroll
      for (int ni = 0; ni < 4; ni++)
        acc[mi][ni] = MFMA16(af[mi], bf4[ni], acc[mi][ni]);
    __syncthreads();
  }

  #pragma unroll
  for (int ni = 0; ni < 4; ni++) {
    const int g = bn + ntb + ni * 16;
    const float bias = Bias[g + l16];
    #pragma unroll
    for (int mi = 0; mi < 4; mi++) {
      const int row0 = bm + mtb + mi * 16 + quad * 4;
      #pragma unroll
      for (int r = 0; r < 4; r++) {
        const size_t idx = (size_t)(row0 + r) * 512 + g + l16;
        OUT[idx] = acc[mi][ni][r] + bias + FT[idx];
      }
    }
  }
}

// ============================================================
extern "C" void kernel_launch(void* const* d_in, const int* in_sizes, int n_in,
                              void* d_out, int out_size, void* d_ws, size_t ws_size,
                              hipStream_t stream) {
  const float* ft    = (const float*)d_in[0];  // [16][1024][512] f32
  const float* w_qkv = (const float*)d_in[1];  // [512][1536]   f32
  const float* b_qkv = (const float*)d_in[2];  // [1536]        f32
  const float* w_out = (const float*)d_in[3];  // [512][512]    f32
  const float* b_out = (const float*)d_in[4];  // [512]         f32
  float* out = (float*)d_out;                  // [16][1024][512] f32

  char* p = (char*)d_ws;
  u16* Xbf    = (u16*)(p);                              // 16,777,216
  u16* ATT    = Xbf;                                    // alias (Xbf dead)
  u16* Wqkv_t = (u16*)(p + 16777216);                   //  1,572,864
  u16* Wout_t = (u16*)(p + 18350080);                   //    524,288
  u16* Qp     = (u16*)(p + 18874368);                   // 16,777,216 (pre-scaled)
  u16* Kp     = (u16*)(p + 35651584);                   // 16,777,216
  u16* Vt     = (u16*)(p + 52428800);                   // 16,777,216 -> 69.2 MB

  conv_x     <<<4096, 256, 0, stream>>>(ft, Xbf);
  transpose_w<<<dim3(48, 16, 2), 256, 0, stream>>>(w_qkv, w_out, Wqkv_t, Wout_t);
  qkv_gemm   <<<dim3(12, 128), 256, 0, stream>>>(Xbf, Wqkv_t, b_qkv, Qp, Kp, Vt);
  attn_mfma  <<<dim3(1024), 512, 0, stream>>>(Qp, Kp, Vt, ATT);
  out_proj   <<<dim3(4, 128), 256, 0, stream>>>(ATT, Wout_t, b_out, ft, out);
}

// Round 8
// 195.777 us; speedup vs baseline: 1.6982x; 1.0324x over previous
//
#include <hip/hip_runtime.h>
#include <hip/hip_bf16.h>

using u16 = unsigned short;
using u32 = unsigned int;
typedef __attribute__((ext_vector_type(8))) short short8;  // 8 bf16 (4 VGPRs)
typedef __attribute__((ext_vector_type(4))) float f32x4;   // MFMA 16x16 C/D

#define MFMA16(A, B, C) __builtin_amdgcn_mfma_f32_16x16x32_bf16((A), (B), (C), 0, 0, 0)

// ---------- bf16 helpers ----------
__device__ __forceinline__ u16 f2bf(float f) {
  union { float f; u32 i; } v; v.f = f;
  u32 x = v.i;
  return (u16)((x + 0x7fffu + ((x >> 16) & 1u)) >> 16);  // RNE
}
__device__ __forceinline__ u32 pkbf(float a, float b) {
  union { __hip_bfloat162 h; u32 u; } v;
  v.h = __float22bfloat162_rn(make_float2(a, b));
  return v.u;
}
// HW packed f32->bf16 (RNE), 1 instr; no builtin on gfx950 (T12/m240)
__device__ __forceinline__ u32 cvtpk(float a, float b) {
  u32 r;
  asm("v_cvt_pk_bf16_f32 %0, %1, %2" : "=v"(r) : "v"(a), "v"(b));
  return r;
}
// async global->LDS, 16B/lane; LDS dest = wave-uniform base + lane*16
__device__ __forceinline__ void gl16(const u16* g, u16* l) {
  __builtin_amdgcn_global_load_lds(
      (const __attribute__((address_space(1))) u32*)g,
      (__attribute__((address_space(3))) u32*)l, 16, 0, 0);
}

// ============================================================
// Prep A: ft fp32 -> Xbf bf16 (16384x512)
// ============================================================
__global__ __launch_bounds__(256) void conv_x(const float* __restrict__ X,
                                              u16* __restrict__ Xbf) {
  const int i = (blockIdx.x * 256 + threadIdx.x) * 8;
  float4 a = *(const float4*)(X + i);
  float4 b = *(const float4*)(X + i + 4);
  uint4 o;
  o.x = pkbf(a.x, a.y); o.y = pkbf(a.z, a.w);
  o.z = pkbf(b.x, b.y); o.w = pkbf(b.z, b.w);
  *(uint4*)(Xbf + i) = o;
}

// ============================================================
// Prep B: transpose+convert W[512][N] fp32 -> Wt[N][512] bf16
// ============================================================
__global__ __launch_bounds__(256) void transpose_w(
    const float* __restrict__ Wq, const float* __restrict__ Wo,
    u16* __restrict__ Wqt, u16* __restrict__ Wot) {
  const int z = blockIdx.z;
  if (z == 1 && blockIdx.x >= 16) return;
  const float* src = z ? Wo : Wq;
  u16* dst = z ? Wot : Wqt;
  const int ncols = z ? 512 : 1536;
  __shared__ float tile[32][33];
  const int t = threadIdx.x;
  const int kt = blockIdx.y * 32, nt = blockIdx.x * 32;
  const int r = t >> 3, c4 = (t & 7) * 4;
  float4 v = *(const float4*)(src + (size_t)(kt + r) * ncols + nt + c4);
  tile[r][c4 + 0] = v.x; tile[r][c4 + 1] = v.y;
  tile[r][c4 + 2] = v.z; tile[r][c4 + 3] = v.w;
  __syncthreads();
  uint2 p = make_uint2(pkbf(tile[c4 + 0][r], tile[c4 + 1][r]),
                       pkbf(tile[c4 + 2][r], tile[c4 + 3][r]));
  *(uint2*)(dst + (size_t)(nt + r) * 512 + kt + c4) = p;
}

// ============================================================
// Kernel 1 v2: QKV GEMM, m97-style staging + 2-phase DOUBLE-BUFFER
// (non-unrolled runtime K-loop). Q pre-scaled by 0.125*log2(e).
// -> Qp[b][h][n][64]*SCALE*log2e, Kp[b][h][n][64], Vt[b][h][64][n]
// ============================================================
__global__ __launch_bounds__(256) void qkv_gemm(
    const u16* __restrict__ Xbf, const u16* __restrict__ Wt,
    const float* __restrict__ Bias,
    u16* __restrict__ Qp, u16* __restrict__ Kp, u16* __restrict__ Vt) {
  __shared__ u16 Xs[2][128][32];  // [buf][m][k] unpadded, 64 B rows
  __shared__ u16 Ws[2][128][32];  // [buf][n][k]
  const int t = threadIdx.x;
  const int bm = blockIdx.y * 128, bn = blockIdx.x * 128;
  const int w = t >> 6, lane = t & 63, quad = lane >> 4, l16 = lane & 15;
  const int mtb = (w >> 1) * 64, ntb = (w & 1) * 64;
  const int rr = lane >> 2;                                  // row in 16-row group
  const int gch = ((lane & 3) ^ ((lane >> 3) & 3)) * 8;      // swizzled global chunk
  const int sw = (quad ^ ((l16 >> 1) & 3)) * 8;              // frag-read chunk

  const u16* xg0 = Xbf + (size_t)(bm + w * 16 + rr) * 512 + gch;
  const u16* xg1 = xg0 + (size_t)64 * 512;
  const u16* wg0 = Wt + (size_t)(bn + w * 16 + rr) * 512 + gch;
  const u16* wg1 = wg0 + (size_t)64 * 512;
  // per-buffer wave-uniform LDS dests
  u16* xl0[2] = {&Xs[0][w * 16][0], &Xs[1][w * 16][0]};
  u16* wl0[2] = {&Ws[0][w * 16][0], &Ws[1][w * 16][0]};

  f32x4 acc[4][4];
  const f32x4 z4 = {0.f, 0.f, 0.f, 0.f};
  #pragma unroll
  for (int mi = 0; mi < 4; mi++)
    #pragma unroll
    for (int ni = 0; ni < 4; ni++) acc[mi][ni] = z4;

  // ---- prologue: stage K-step 0 into buffer 0 ----
  gl16(xg0, xl0[0]); gl16(xg1, xl0[0] + 2048);
  gl16(wg0, wl0[0]); gl16(wg1, wl0[0] + 2048);
  __syncthreads();

  for (int k0 = 0; k0 < 512; k0 += 32) {   // runtime loop (v8 spill lesson)
    const int cur = (k0 >> 5) & 1;
    if (k0 < 480) {                        // issue next step into buf^1
      const int nxt = cur ^ 1, kn = k0 + 32;
      gl16(xg0 + kn, xl0[nxt]); gl16(xg1 + kn, xl0[nxt] + 2048);
      gl16(wg0 + kn, wl0[nxt]); gl16(wg1 + kn, wl0[nxt] + 2048);
    }
    short8 af[4], bf4[4];
    #pragma unroll
    for (int mi = 0; mi < 4; mi++)
      af[mi] = *(const short8*)&Xs[cur][mtb + mi * 16 + l16][sw];
    #pragma unroll
    for (int ni = 0; ni < 4; ni++)
      bf4[ni] = *(const short8*)&Ws[cur][ntb + ni * 16 + l16][sw];
    #pragma unroll
    for (int mi = 0; mi < 4; mi++)
      #pragma unroll
      for (int ni = 0; ni < 4; ni++)
        acc[mi][ni] = MFMA16(af[mi], bf4[ni], acc[mi][ni]);
    // ONE barrier: drains next-step DMA (had whole compute to land)
    // and fences this buffer's reads before step+2 overwrites it.
    __syncthreads();
  }

  // epilogue: C-layout (row=quad*4+r, col=l16) -> packed Q/K/V
  #pragma unroll
  for (int ni = 0; ni < 4; ni++) {
    const int g = bn + ntb + ni * 16;
    const int h = g / 192, rm = g % 192;
    const int type = rm >> 6, dbase = rm & 63;
    const float bias = Bias[g + l16];
    // fold softmax scale AND log2(e) into Q so attn uses exp2 natively
    const float qsc = (type == 0) ? 0.125f * 1.44269504088896340736f : 1.0f;
    #pragma unroll
    for (int mi = 0; mi < 4; mi++) {
      const int row0 = bm + mtb + mi * 16 + quad * 4;
      const int b = row0 >> 10, n0 = row0 & 1023;
      const size_t bh = (size_t)(b * 8 + h) * 65536;
      if (type == 2) {  // V -> Vt[b][h][d][n]
        uint2 p = make_uint2(pkbf(acc[mi][ni][0] + bias, acc[mi][ni][1] + bias),
                             pkbf(acc[mi][ni][2] + bias, acc[mi][ni][3] + bias));
        *(uint2*)(Vt + bh + (size_t)(dbase + l16) * 1024 + n0) = p;
      } else {
        u16* dst = (type ? Kp : Qp) + bh;
        #pragma unroll
        for (int r = 0; r < 4; r++)
          dst[(size_t)(n0 + r) * 64 + dbase + l16] =
              f2bf((acc[mi][ni][r] + bias) * qsc);
      }
    }
  }
}

// ============================================================
// Kernel 2 v10: flash attention, KVBLK 128 -> 64 for FULL occupancy:
// LDS = 2buf x (K 8KB + V 8KB) = 32 KB -> 4 blocks/CU resident
// (= 2048 threads = 100%); launch_bounds(512,8) caps VGPR at 64
// (v9 measured exactly 64 with MORE live state; e/o halved here).
// Same S^T formulation, no P LDS, no online-max, DMA staging with
// pre-swizzled global source, 2-phase dbuf, runtime loop (16 kt).
// P pack now via HW v_cvt_pk_bf16_f32 (1 instr vs ~10 software RNE).
// Per-kt: nt 0..3 (4 S-tiles), e[4]/o[4], permlane x4, ks 0..1,
// 16 MFMA total -- same algebra as v9 with arrays halved.
// ============================================================
__global__ __launch_bounds__(512, 8) void attn_mfma(
    const u16* __restrict__ Qp, const u16* __restrict__ Kp,
    const u16* __restrict__ Vt, u16* __restrict__ ATT) {
  __shared__ u16 Ks[2][64][64];   // [buf][key][d]   linear, swizzled content
  __shared__ u16 Vs[2][64][64];   // [buf][d][key]   linear, swizzled content
  const int t = threadIdx.x, w = t >> 6, lane = t & 63;
  const int quad = lane >> 4, l16 = lane & 15;
  const int bx = blockIdx.x;
  const int c = bx & 7, g = bx >> 3;
  const int qt = g & 7, u = g >> 3;
  const int bh_id = u * 8 + c;
  const int b = bh_id >> 3, h = bh_id & 7;
  const size_t bh = (size_t)bh_id * 65536;
  const u16* Qb = Qp + bh;
  const u16* Kb = Kp + bh;
  const u16* Vb = Vt + bh;
  const int q0 = qt * 128 + w * 16;

  // ---- DMA source addresses (inverse-swizzled global chunks) ----
  // K tile: 64 keys x 64 d = 8KB = 512 lanes x 16B. LDS slot byte
  // t*16 = row r=t>>3 (128B rows), chunk c'=t&7; global chunk c'^(r&7).
  const u16* kg = Kb + (size_t)(t >> 3) * 64 + ((t & 7) ^ ((t >> 3) & 7)) * 8;
  // V tile: 64 d-rows x 64 keys; row d=t>>3, key-chunk c'=t&7.
  const u16* vg = Vb + (size_t)(t >> 3) * 1024 + ((t & 7) ^ ((t >> 3) & 7)) * 8;
  // wave-uniform LDS dests (1 KiB per wave), per buffer
  u16* ks0 = &Ks[0][0][0] + w * 512;
  u16* ks1 = &Ks[1][0][0] + w * 512;
  u16* vs0 = &Vs[0][0][0] + w * 512;
  u16* vs1 = &Vs[1][0][0] + w * 512;

  // ---- read-side swizzled base offsets (bytes), hoisted ----
  const int m7 = l16 & 7;
  const char* ksb = (const char*)&Ks[0][0][0];
  const char* vsb = (const char*)&Vs[0][0][0];
  const int kb0 = l16 * 128 + (quad ^ m7) * 16;   // d-chunk quad
  const int kb1 = kb0 ^ 64;                       // d-chunk quad+4
  int vo[2];
  #pragma unroll
  for (int ks = 0; ks < 2; ks++)                  // key-chunk 4ks+quad
    vo[ks] = l16 * 128 + ((4 * ks + quad) ^ m7) * 16;

  // Q frags (B-operand for S^T): 8 regs
  short8 qf[2];
  #pragma unroll
  for (int ks = 0; ks < 2; ks++)
    qf[ks] = *(const short8*)(Qb + (size_t)(q0 + l16) * 64 + ks * 32 + quad * 8);

  float l_ = 0.f;
  f32x4 Of[4];
  const f32x4 z4 = {0.f, 0.f, 0.f, 0.f};
  #pragma unroll
  for (int ni = 0; ni < 4; ni++) Of[ni] = z4;

  // ---- prologue: stage tile 0 into buffer 0 ----
  gl16(kg, ks0);
  gl16(vg, vs0);
  __syncthreads();   // drain prologue DMA

  for (int kt = 0; kt < 16; ++kt) {   // runtime loop (v8 spill lesson)
    const int cur = kt & 1;
    if (kt < 15) {
      gl16(kg + (kt + 1) * 4096, cur ? ks0 : ks1);
      gl16(vg + (kt + 1) * 64,   cur ? vs0 : vs1);
    }
    const int co = cur << 13;  // byte offset of current buffer (8192)

    // ---- S^T tiles + fused softmax/pack: lane owns query q0+l16,
    //      keys {16nt + 4quad + r}, nt 0..3 ----
    u32 e[4], o[4];  // even-nt / odd-nt packed bf16 pairs
    #pragma unroll
    for (int nt = 0; nt < 4; nt++) {
      short8 k0f = *(const short8*)(ksb + co + kb0 + nt * 2048);
      short8 k1f = *(const short8*)(ksb + co + kb1 + nt * 2048);
      f32x4 s = z4;
      s = MFMA16(k0f, qf[0], s);
      s = MFMA16(k1f, qf[1], s);
      float p0 = __builtin_amdgcn_exp2f(s[0]);
      float p1 = __builtin_amdgcn_exp2f(s[1]);
      float p2 = __builtin_amdgcn_exp2f(s[2]);
      float p3 = __builtin_amdgcn_exp2f(s[3]);
      l_ += (p0 + p1) + (p2 + p3);   // per-lane partial; reduced in epilogue
      const u32 lo = cvtpk(p0, p1), hi = cvtpk(p2, p3);
      if (nt & 1) { o[(nt >> 1) * 2] = lo; o[(nt >> 1) * 2 + 1] = hi; }
      else        { e[(nt >> 1) * 2] = lo; e[(nt >> 1) * 2 + 1] = hi; }
    }
    // ---- cross-quad P redistribution, in-register, IN PLACE ----
    // pl32swap then pl16swap: e' = {E(q0),E(q2),O(q0),O(q2)},
    //                         o' = {E(q1),E(q3),O(q1),O(q3)}
    // => A-frag(q,ks) = {e'[2ks],e'[2ks+1],o'[2ks],o'[2ks+1]}
    #pragma unroll
    for (int i = 0; i < 4; i++) {
      auto t01 = __builtin_amdgcn_permlane32_swap(e[i], o[i], false, false);
      auto xy  = __builtin_amdgcn_permlane16_swap(t01[0], t01[1], false, false);
      e[i] = xy[0]; o[i] = xy[1];
    }
    // ---- O += P V (8 MFMA), P-frags straight from registers ----
    #pragma unroll
    for (int ks = 0; ks < 2; ks++) {
      union { short8 v; u32 u[4]; } pa;
      pa.u[0] = e[2 * ks]; pa.u[1] = e[2 * ks + 1];
      pa.u[2] = o[2 * ks]; pa.u[3] = o[2 * ks + 1];
      #pragma unroll
      for (int ni = 0; ni < 4; ni++) {
        short8 vf = *(const short8*)(vsb + co + vo[ks] + ni * 2048);
        Of[ni] = MFMA16(pa.v, vf, Of[ni]);
      }
    }
    // ONE barrier per kt: implicit vmcnt(0) drains next-tile DMA;
    // also fences this buffer's reads before kt+1 overwrites it.
    __syncthreads();
  }
  // ---- epilogue: reduce l across quads (lanes l16,l16+16,+32,+48
  //      hold the 4 quad-partials of query l16), then normalize ----
  l_ += __shfl_xor(l_, 16);
  l_ += __shfl_xor(l_, 32);
  float lv[4];
  #pragma unroll
  for (int r = 0; r < 4; r++) lv[r] = __shfl(l_, quad * 4 + r);
  #pragma unroll
  for (int r = 0; r < 4; r++) {
    const float inv = 1.0f / lv[r];
    const int row = b * 1024 + q0 + quad * 4 + r;
    #pragma unroll
    for (int ni = 0; ni < 4; ni++)
      ATT[(size_t)row * 512 + h * 64 + ni * 16 + l16] = f2bf(Of[ni][r] * inv);
  }
}

// ============================================================
// Kernel 3 v2: OUT = ATT(bf16) @ Wout^T + bias + ft(f32) -> f32
// Same 2-phase double-buffered staging as qkv_gemm v2.
// ============================================================
__global__ __launch_bounds__(256) void out_proj(
    const u16* __restrict__ A, const u16* __restrict__ Wt,
    const float* __restrict__ Bias, const float* __restrict__ FT,
    float* __restrict__ OUT) {
  __shared__ u16 As[2][128][32];
  __shared__ u16 Ws[2][128][32];
  const int t = threadIdx.x;
  const int bm = blockIdx.y * 128, bn = blockIdx.x * 128;
  const int w = t >> 6, lane = t & 63, quad = lane >> 4, l16 = lane & 15;
  const int mtb = (w >> 1) * 64, ntb = (w & 1) * 64;
  const int rr = lane >> 2;
  const int gch = ((lane & 3) ^ ((lane >> 3) & 3)) * 8;
  const int sw = (quad ^ ((l16 >> 1) & 3)) * 8;

  const u16* ag0 = A + (size_t)(bm + w * 16 + rr) * 512 + gch;
  const u16* ag1 = ag0 + (size_t)64 * 512;
  const u16* wg0 = Wt + (size_t)(bn + w * 16 + rr) * 512 + gch;
  const u16* wg1 = wg0 + (size_t)64 * 512;
  u16* al0[2] = {&As[0][w * 16][0], &As[1][w * 16][0]};
  u16* wl0[2] = {&Ws[0][w * 16][0], &Ws[1][w * 16][0]};

  f32x4 acc[4][4];
  const f32x4 z4 = {0.f, 0.f, 0.f, 0.f};
  #pragma unroll
  for (int mi = 0; mi < 4; mi++)
    #pragma unroll
    for (int ni = 0; ni < 4; ni++) acc[mi][ni] = z4;

  // ---- prologue: stage K-step 0 into buffer 0 ----
  gl16(ag0, al0[0]); gl16(ag1, al0[0] + 2048);
  gl16(wg0, wl0[0]); gl16(wg1, wl0[0] + 2048);
  __syncthreads();

  for (int k0 = 0; k0 < 512; k0 += 32) {   // runtime loop
    const int cur = (k0 >> 5) & 1;
    if (k0 < 480) {
      const int nxt = cur ^ 1, kn = k0 + 32;
      gl16(ag0 + kn, al0[nxt]); gl16(ag1 + kn, al0[nxt] + 2048);
      gl16(wg0 + kn, wl0[nxt]); gl16(wg1 + kn, wl0[nxt] + 2048);
    }
    short8 af[4], bf4[4];
    #pragma unroll
    for (int mi = 0; mi < 4; mi++)
      af[mi] = *(const short8*)&As[cur][mtb + mi * 16 + l16][sw];
    #pragma unroll
    for (int ni = 0; ni < 4; ni++)
      bf4[ni] = *(const short8*)&Ws[cur][ntb + ni * 16 + l16][sw];
    #pragma unroll
    for (int mi = 0; mi < 4; mi++)
      #pragma unroll
      for (int ni = 0; ni < 4; ni++)
        acc[mi][ni] = MFMA16(af[mi], bf4[ni], acc[mi][ni]);
    __syncthreads();
  }

  #pragma unroll
  for (int ni = 0; ni < 4; ni++) {
    const int g = bn + ntb + ni * 16;
    const float bias = Bias[g + l16];
    #pragma unroll
    for (int mi = 0; mi < 4; mi++) {
      const int row0 = bm + mtb + mi * 16 + quad * 4;
      #pragma unroll
      for (int r = 0; r < 4; r++) {
        const size_t idx = (size_t)(row0 + r) * 512 + g + l16;
        OUT[idx] = acc[mi][ni][r] + bias + FT[idx];
      }
    }
  }
}

// ============================================================
extern "C" void kernel_launch(void* const* d_in, const int* in_sizes, int n_in,
                              void* d_out, int out_size, void* d_ws, size_t ws_size,
                              hipStream_t stream) {
  const float* ft    = (const float*)d_in[0];  // [16][1024][512] f32
  const float* w_qkv = (const float*)d_in[1];  // [512][1536]   f32
  const float* b_qkv = (const float*)d_in[2];  // [1536]        f32
  const float* w_out = (const float*)d_in[3];  // [512][512]    f32
  const float* b_out = (const float*)d_in[4];  // [512]         f32
  float* out = (float*)d_out;                  // [16][1024][512] f32

  char* p = (char*)d_ws;
  u16* Xbf    = (u16*)(p);                              // 16,777,216
  u16* ATT    = Xbf;                                    // alias (Xbf dead)
  u16* Wqkv_t = (u16*)(p + 16777216);                   //  1,572,864
  u16* Wout_t = (u16*)(p + 18350080);                   //    524,288
  u16* Qp     = (u16*)(p + 18874368);                   // 16,777,216 (pre-scaled)
  u16* Kp     = (u16*)(p + 35651584);                   // 16,777,216
  u16* Vt     = (u16*)(p + 52428800);                   // 16,777,216 -> 69.2 MB

  conv_x     <<<4096, 256, 0, stream>>>(ft, Xbf);
  transpose_w<<<dim3(48, 16, 2), 256, 0, stream>>>(w_qkv, w_out, Wqkv_t, Wout_t);
  qkv_gemm   <<<dim3(12, 128), 256, 0, stream>>>(Xbf, Wqkv_t, b_qkv, Qp, Kp, Vt);
  attn_mfma  <<<dim3(1024), 512, 0, stream>>>(Qp, Kp, Vt, ATT);
  out_proj   <<<dim3(4, 128), 256, 0, stream>>>(ATT, Wout_t, b_out, ft, out);
}